// Round 17
// baseline (129.957 us; speedup 1.0000x reference)
//
#include <hip/hip_runtime.h>
#include <hip/hip_bf16.h>

#define D_MODEL 1024
#define NHEADS  16
#define HDIM    64
#define SEQ     2048
#define BATCH   2
#define MROWS   (BATCH * SEQ)   // 4096
#define CHELEM  ((size_t)BATCH * NHEADS * SEQ * HDIM)  // 4194304

typedef __bf16 bf16x8 __attribute__((ext_vector_type(8)));
typedef float  f32x4  __attribute__((ext_vector_type(4)));

__device__ __forceinline__ unsigned short f2bf(float f) {
  unsigned u = __builtin_bit_cast(unsigned, f);
  return (unsigned short)((u + 0x7fffu + ((u >> 16) & 1u)) >> 16);
}

__device__ __forceinline__ float fexp2(float x) {
#if __has_builtin(__builtin_amdgcn_exp2f)
  return __builtin_amdgcn_exp2f(x);
#else
  return __expf(x * 0.6931471805599453f);
#endif
}

__device__ __forceinline__ f32x4 mfma16(bf16x8 a, bf16x8 b, f32x4 c) {
  return __builtin_amdgcn_mfma_f32_16x16x32_bf16(a, b, c, 0, 0, 0);
}

__device__ __forceinline__ void gll16(const unsigned short* g, unsigned short* l) {
  __builtin_amdgcn_global_load_lds(
      (const __attribute__((address_space(1))) unsigned*)g,
      (__attribute__((address_space(3))) unsigned*)l, 16, 0, 0);
}

__global__ void cvt_f32_bf16(const float* __restrict__ in,
                             unsigned short* __restrict__ out, int n4) {
  int i = blockIdx.x * blockDim.x + threadIdx.x;
  if (i >= n4) return;
  float4 v = reinterpret_cast<const float4*>(in)[i];
  ushort4 o;
  o.x = f2bf(v.x); o.y = f2bf(v.y); o.z = f2bf(v.z); o.w = f2bf(v.w);
  reinterpret_cast<ushort4*>(out)[i] = o;
}

// fused conversion of the 4 weight matrices (saves 3 launches)
__global__ void cvt_w4(const float* __restrict__ s0, const float* __restrict__ s1,
                       const float* __restrict__ s2, const float* __restrict__ s3,
                       unsigned short* __restrict__ d0, unsigned short* __restrict__ d1,
                       unsigned short* __restrict__ d2, unsigned short* __restrict__ d3) {
  int i = blockIdx.x * blockDim.x + threadIdx.x;  // n4 = D*D/4
  const int y = blockIdx.y;
  const float* s = (y == 0) ? s0 : (y == 1) ? s1 : (y == 2) ? s2 : s3;
  unsigned short* d = (y == 0) ? d0 : (y == 1) ? d1 : (y == 2) ? d2 : d3;
  float4 v = reinterpret_cast<const float4*>(s)[i];
  ushort4 o;
  o.x = f2bf(v.x); o.y = f2bf(v.y); o.z = f2bf(v.z); o.w = f2bf(v.w);
  reinterpret_cast<ushort4*>(d)[i] = o;
}

// C = A[M,K] * Bt[N,K]^T + bias  (global_load_lds staging, m97 pattern,
// 16B-chunk XOR swizzle on LDS tiles; conflicts = 0, r16-verified).
// MODE 2: out f32 row-major [M,N]  (final projection, bias=b0)
// MODE 3: fused QKV: N=3072; chunk 0->Q [B,H,S,64] (PRE-SCALED by
//         0.125*log2e for exp2-domain softmax), 1->K, 2->V^T [B,H,64,S]
template <int MODE>
__global__ __launch_bounds__(256) void gemm_bt2(
    const unsigned short* __restrict__ A,
    const unsigned short* __restrict__ Bt,
    const float* __restrict__ b0, const float* __restrict__ b1,
    const float* __restrict__ b2,
    void* __restrict__ outp, int M, int N, int K) {
  __shared__ __align__(16) unsigned short lA[128 * 32];
  __shared__ __align__(16) unsigned short lB[128 * 32];
  const int tid = threadIdx.x;
  const int m0 = blockIdx.y * 128, n0 = blockIdx.x * 128;
  const int lane = tid & 63, wid = tid >> 6;
  const int wr = wid >> 1, wc = wid & 1;
  const int fr = lane & 15, g = lane >> 4;

  const int srow = wid * 32 + (lane >> 2);
  const int scol = ((lane & 3) ^ ((lane >> 3) & 3)) * 8;
  const unsigned short* gA = A + (size_t)(m0 + srow) * K + scol;
  const unsigned short* gB = Bt + (size_t)(n0 + srow) * K + scol;
  unsigned short* lAw = lA + wid * 1024;
  unsigned short* lBw = lB + wid * 1024;

  const int rswz = (g ^ ((fr >> 1) & 3)) * 8;

  f32x4 acc[4][4];
#pragma unroll
  for (int i = 0; i < 4; ++i)
#pragma unroll
    for (int j = 0; j < 4; ++j) acc[i][j] = (f32x4){0.f, 0.f, 0.f, 0.f};

  for (int kt = 0; kt < K; kt += 32) {
    gll16(gA + kt, lAw);
    gll16(gA + (size_t)16 * K + kt, lAw + 512);
    gll16(gB + kt, lBw);
    gll16(gB + (size_t)16 * K + kt, lBw + 512);
    __syncthreads();
    bf16x8 af[4], bfv[4];
#pragma unroll
    for (int i = 0; i < 4; ++i)
      af[i] = *reinterpret_cast<const bf16x8*>(
          &lA[(wr * 64 + i * 16 + fr) * 32 + rswz]);
#pragma unroll
    for (int j = 0; j < 4; ++j)
      bfv[j] = *reinterpret_cast<const bf16x8*>(
          &lB[(wc * 64 + j * 16 + fr) * 32 + rswz]);
#pragma unroll
    for (int i = 0; i < 4; ++i)
#pragma unroll
      for (int j = 0; j < 4; ++j)
        acc[i][j] = mfma16(af[i], bfv[j], acc[i][j]);
    __syncthreads();
  }

  const int src = n0 >> 10;
  const float* bp = (MODE == 2) ? b0 : (src == 0 ? b0 : (src == 1 ? b1 : b2));
#pragma unroll
  for (int i = 0; i < 4; ++i)
#pragma unroll
    for (int j = 0; j < 4; ++j)
#pragma unroll
      for (int r = 0; r < 4; ++r) {
        int m = m0 + wr * 64 + i * 16 + g * 4 + r;
        int n = n0 + wc * 64 + j * 16 + fr;
        if (MODE == 2) {
          float val = acc[i][j][r] + bp[n];
          reinterpret_cast<float*>(outp)[(size_t)m * N + n] = val;
        } else {
          int within = n & 1023;
          float val = acc[i][j][r] + bp[within];
          if (src == 0) val *= 0.1803368867f;  // 0.125 * log2(e)
          int b = m >> 11, s = m & 2047;
          int hh = within >> 6, dh = within & 63;
          size_t idx;
          if (src != 2)
            idx = ((size_t)(b * NHEADS + hh) * SEQ + s) * HDIM + dh;
          else
            idx = ((size_t)(b * NHEADS + hh) * HDIM + dh) * SEQ + s;
          reinterpret_cast<unsigned short*>(outp)[(size_t)src * CHELEM + idx] =
              f2bf(val);
        }
      }
}

// Flash attention, swapped-operand + SPLIT-K wave pairs on the cooperative
// staged skeleton: 8 waves/block (rho=wid>>2 takes even/odd k-tiles of the
// q-tile qsel=wid&3). Each interval stages TWO tiles (32KB slot, dbuf=64KB,
// 2 blocks/CU -> 4 waves/SIMD). Intervals/block = 17 exactly for all j
// (balance preserved). Exact (m,l,O) merge per pass via LDS (r11-proven
// formula), merge buffer aliased over staging LDS (barrier-protected).
// Q,K: [B,H,S,64] bf16 ; Vt: [B,H,64,S] bf16 ; O: [B,S,1024] bf16
__global__ __launch_bounds__(512) void attn_fwd13(
    const unsigned short* __restrict__ Q,
    const unsigned short* __restrict__ Km,
    const unsigned short* __restrict__ Vt,
    unsigned short* __restrict__ O) {
  const int tid = threadIdx.x;
  const int lane = tid & 63, wid = tid >> 6;
  const int fr = lane & 15, g = lane >> 4;
  const int rho = wid >> 2, qsel = wid & 3;
  // XCD-grouped decode: lin%8 = XCD; 16 blocks per (b,h) slab on one XCD.
  const int lin = blockIdx.x;            // 0..511
  const int c = lin & 7;
  const int t = lin >> 3;                // 0..63
  const int j = t & 15;                  // block's pair index 0..15
  const int sgrp = t >> 4;               // 0..3
  const int slab = sgrp * 8 + c;         // 0..31
  const int b = slab >> 4, h = slab & 15;
  const int bh = b * NHEADS + h;

  // 64KB: slot s at s*16384 (shorts); K sub t at +t*4096; V at +8192+t*4096
  __shared__ __align__(16) unsigned short lsm[32768];

  const unsigned short* kptr = Km + (size_t)bh * SEQ * HDIM;
  const unsigned short* vptr = Vt + (size_t)bh * HDIM * SEQ;

  // staging: thread covers row sr (0..63), chunk sch of one 8KB tile
  const int sr = tid >> 3;
  const int sch = tid & 7;
  const int schx = ((sch ^ (sr & 7)) << 3);  // pre-swizzled 16B chunk
  const int kswz0 = ((g ^ (fr & 7)) << 3);        // ch = g
  const int kswz1 = (((4 + g) ^ (fr & 7)) << 3);  // ch = 4+g
  const int g2 = g >> 1, gh = (g & 1) * 4;
  const int vlo0 = (((0 + g2) ^ (fr & 7)) << 3) + gh;
  const int vhi0 = (((2 + g2) ^ (fr & 7)) << 3) + gh;
  const int vlo1 = (((4 + g2) ^ (fr & 7)) << 3) + gh;
  const int vhi1 = (((6 + g2) ^ (fr & 7)) << 3) + gh;

  // stage tile KT into slot S, subslot SUB (block-uniform args)
#define STAGE1(S, SUB, KT)                                                  \
  { const int n0s = (KT) * 64;                                              \
    gll16(kptr + (size_t)(n0s + sr) * HDIM + schx,                          \
          &lsm[(S) * 16384 + (SUB) * 4096 + wid * 512]);                    \
    gll16(vptr + (size_t)sr * SEQ + n0s + schx,                             \
          &lsm[(S) * 16384 + 8192 + (SUB) * 4096 + wid * 512]); }

#pragma unroll 1
  for (int pass = 0; pass < 2; ++pass) {
    const int qt = pass ? (124 - 4 * j + qsel) : (4 * j + qsel);
    const int q0 = qt * 16;
    const int nkt = pass ? (32 - j) : (j + 1);  // block-uniform
    const int ni = (nkt + 1) >> 1;
    const int qg = q0 + fr;

    const unsigned short* qb = Q + ((size_t)bh * SEQ + qg) * HDIM + g * 8;
    bf16x8 qa0 = *reinterpret_cast<const bf16x8*>(qb);
    bf16x8 qa1 = *reinterpret_cast<const bf16x8*>(qb + 32);

    f32x4 oacc[4];
#pragma unroll
    for (int i = 0; i < 4; ++i) oacc[i] = (f32x4){0.f, 0.f, 0.f, 0.f};
    float mreg = -3e30f;
    float lrow = 0.f;

    STAGE1(0, 0, 0);
    if (1 < nkt) STAGE1(0, 1, 1);
    __syncthreads();

    for (int i = 0; i < ni; ++i) {
      const int s = i & 1;
      // prefetch next interval's tile pair
      if (2 * (i + 1) < nkt) STAGE1(s ^ 1, 0, 2 * (i + 1));
      if (2 * (i + 1) + 1 < nkt) STAGE1(s ^ 1, 1, 2 * (i + 1) + 1);
      const int kt = 2 * i + rho;
      if (kt < nkt) {
        const int n0 = kt * 64;
        const unsigned short* Kb = &lsm[s * 16384 + rho * 4096];
        const unsigned short* Vb = &lsm[s * 16384 + 8192 + rho * 4096];
        // K fragments as A-operand
        bf16x8 kf0[4], kf1[4];
#pragma unroll
        for (int cc = 0; cc < 4; ++cc) {
          kf0[cc] = *reinterpret_cast<const bf16x8*>(
              &Kb[(cc * 16 + fr) * 64 + kswz0]);
          kf1[cc] = *reinterpret_cast<const bf16x8*>(
              &Kb[(cc * 16 + fr) * 64 + kswz1]);
        }
        // S' = K * Q^T
        f32x4 sacc[4];
#pragma unroll
        for (int cc = 0; cc < 4; ++cc) {
          sacc[cc] = (f32x4){0.f, 0.f, 0.f, 0.f};
          sacc[cc] = mfma16(kf0[cc], qa0, sacc[cc]);
          sacc[cc] = mfma16(kf1[cc], qa1, sacc[cc]);
        }
        // mask (global-last tile only; its parity selects this wave)
        float sv[4][4];
        float lmax = -3e30f;
        if (kt == nkt - 1) {
#pragma unroll
          for (int cc = 0; cc < 4; ++cc)
#pragma unroll
            for (int r = 0; r < 4; ++r) {
              sv[cc][r] =
                  (n0 + cc * 16 + g * 4 + r <= qg) ? sacc[cc][r] : -1e30f;
              lmax = fmaxf(lmax, sv[cc][r]);
            }
        } else {
#pragma unroll
          for (int cc = 0; cc < 4; ++cc)
#pragma unroll
            for (int r = 0; r < 4; ++r) {
              sv[cc][r] = sacc[cc][r];
              lmax = fmaxf(lmax, sv[cc][r]);
            }
        }
        // defer-max (log2 domain)
        if (!__all(lmax - mreg <= 11.5f)) {
          float tm = lmax;
          tm = fmaxf(tm, __shfl_xor(tm, 16, 64));
          tm = fmaxf(tm, __shfl_xor(tm, 32, 64));
          const float mn = fmaxf(mreg, tm);
          const float al = fexp2(mreg - mn);
          mreg = mn;
          lrow *= al;
#pragma unroll
          for (int nf = 0; nf < 4; ++nf) oacc[nf] *= al;
        }
        // P pack in-lane (pi permutation)
        union { __bf16 e[8]; bf16x8 v; } pk0, pk1;
#pragma unroll
        for (int r = 0; r < 4; ++r) {
          float p0 = fexp2(sv[0][r] - mreg);
          float p1 = fexp2(sv[1][r] - mreg);
          float p2 = fexp2(sv[2][r] - mreg);
          float p3 = fexp2(sv[3][r] - mreg);
          lrow += (p0 + p1) + (p2 + p3);
          pk0.e[r] = (__bf16)p0; pk0.e[4 + r] = (__bf16)p1;
          pk1.e[r] = (__bf16)p2; pk1.e[4 + r] = (__bf16)p3;
        }
        // O^T += V^T * P^T
#pragma unroll
        for (int nf = 0; nf < 4; ++nf) {
          const int vrow = (nf * 16 + fr) * 64;
          union { unsigned long long d[2]; bf16x8 v; } v0, v1;
          v0.d[0] = *reinterpret_cast<const unsigned long long*>(&Vb[vrow + vlo0]);
          v0.d[1] = *reinterpret_cast<const unsigned long long*>(&Vb[vrow + vhi0]);
          v1.d[0] = *reinterpret_cast<const unsigned long long*>(&Vb[vrow + vlo1]);
          v1.d[1] = *reinterpret_cast<const unsigned long long*>(&Vb[vrow + vhi1]);
          oacc[nf] = mfma16(v0.v, pk0.v, oacc[nf]);
          oacc[nf] = mfma16(v1.v, pk1.v, oacc[nf]);
        }
      }
      __syncthreads();  // next pair staged; reads of slot s done
    }

    // ---- exact split-K merge (r11 formula) through aliased LDS ----
    {
      char* mb = reinterpret_cast<char*>(lsm);
      const int moff = qsel * 5120 + lane * 80;
      if (rho == 1) {
#pragma unroll
        for (int nf = 0; nf < 4; ++nf)
          *reinterpret_cast<f32x4*>(mb + moff + nf * 16) = oacc[nf];
        *reinterpret_cast<float*>(mb + moff + 64) = mreg;
        *reinterpret_cast<float*>(mb + moff + 68) = lrow;
      }
      __syncthreads();
      if (rho == 0) {
        f32x4 oB[4];
#pragma unroll
        for (int nf = 0; nf < 4; ++nf)
          oB[nf] = *reinterpret_cast<const f32x4*>(mb + moff + nf * 16);
        const float mB = *reinterpret_cast<const float*>(mb + moff + 64);
        const float lB = *reinterpret_cast<const float*>(mb + moff + 68);
        const float M = fmaxf(mreg, mB);
        const float aA = fexp2(mreg - M);
        const float aB = fexp2(mB - M);
        float lsum = lrow * aA + lB * aB;
        lsum += __shfl_xor(lsum, 16, 64);
        lsum += __shfl_xor(lsum, 32, 64);
        const float inv = 1.f / lsum;
        const size_t obase =
            ((size_t)b * SEQ + qg) * D_MODEL + h * HDIM + g * 4;
#pragma unroll
        for (int nf = 0; nf < 4; ++nf) {
          ushort4 o4;
          o4.x = f2bf((oacc[nf][0] * aA + oB[nf][0] * aB) * inv);
          o4.y = f2bf((oacc[nf][1] * aA + oB[nf][1] * aB) * inv);
          o4.z = f2bf((oacc[nf][2] * aA + oB[nf][2] * aB) * inv);
          o4.w = f2bf((oacc[nf][3] * aA + oB[nf][3] * aB) * inv);
          *reinterpret_cast<ushort4*>(&O[obase + nf * 16]) = o4;
        }
      }
      __syncthreads();  // mergebuf reads done before next pass stages
    }
  }
#undef STAGE1
}

extern "C" void kernel_launch(void* const* d_in, const int* in_sizes, int n_in,
                              void* d_out, int out_size, void* d_ws,
                              size_t ws_size, hipStream_t stream) {
  const float* x  = (const float*)d_in[0];
  const float* wq = (const float*)d_in[1];
  const float* bq = (const float*)d_in[2];
  const float* wk = (const float*)d_in[3];
  const float* bk = (const float*)d_in[4];
  const float* wv = (const float*)d_in[5];
  const float* bv = (const float*)d_in[6];
  const float* wo = (const float*)d_in[7];
  const float* bo = (const float*)d_in[8];
  float* out = (float*)d_out;

  char* w = (char*)d_ws;
  unsigned short* xb    = (unsigned short*)w; w += (size_t)MROWS * D_MODEL * 2;
  unsigned short* wqkvb = (unsigned short*)w; w += (size_t)3 * D_MODEL * D_MODEL * 2;
  unsigned short* wob   = (unsigned short*)w; w += (size_t)D_MODEL * D_MODEL * 2;
  unsigned short* Qb    = (unsigned short*)w; w += CHELEM * 2 * 3;  // Q,K,Vt
  unsigned short* Ob    = (unsigned short*)w; w += (size_t)MROWS * D_MODEL * 2;
  unsigned short* Kb  = Qb + CHELEM;
  unsigned short* Vtb = Qb + 2 * CHELEM;

  {
    int n4 = MROWS * D_MODEL / 4;
    cvt_f32_bf16<<<n4 / 256, 256, 0, stream>>>(x, xb, n4);
  }
  {
    int n4 = D_MODEL * D_MODEL / 4;  // 262144 -> 1024 blocks x 4
    cvt_w4<<<dim3(n4 / 256, 4), 256, 0, stream>>>(
        wq, wk, wv, wo, wqkvb, wqkvb + (size_t)D_MODEL * D_MODEL,
        wqkvb + (size_t)2 * D_MODEL * D_MODEL, wob);
  }

  // fused QKV projection: N = 3072
  gemm_bt2<3><<<dim3(3 * D_MODEL / 128, MROWS / 128), 256, 0, stream>>>(
      xb, wqkvb, bq, bk, bv, Qb, MROWS, 3 * D_MODEL, D_MODEL);

  attn_fwd13<<<512, 512, 0, stream>>>(Qb, Kb, Vtb, Ob);

  gemm_bt2<2><<<dim3(D_MODEL / 128, MROWS / 128), 256, 0, stream>>>(
      Ob, wob, bo, bo, bo, out, MROWS, D_MODEL, D_MODEL);
}